// Round 5
// baseline (114.207 us; speedup 1.0000x reference)
//
#include <hip/hip_runtime.h>
#include <hip/hip_bf16.h>
#include <math.h>

#define NN 512
#define L2E 1.44269504089f
typedef __attribute__((ext_vector_type(8))) short short8;
typedef __attribute__((ext_vector_type(4))) float f32x4;

// ws float offsets
#define OFF_XLI  0u         // interleaved xl: [inst][t=j>>6][q=d>>2][j&63][d&3]
#define OFF_XR   524288u
#define OFF_VV   1048576u
#define OFF_SA   1056768u
#define OFF_XLTH 1056896u   // bf16 hi, transposed [inst][d][j]
#define OFF_XLTL 1319040u   // bf16 lo
#define OFF_H1   1581184u
#define OFF_H2   2105472u

// ---------------- GEMM + v/sa + interleaved & transposed copies ----------------
template<int K>
__global__ __launch_bounds__(256) void kpre(
    const float* __restrict__ src, int srcPerInst,
    const float* __restrict__ Wl0, const float* __restrict__ Wr0, const float* __restrict__ a0,
    const float* __restrict__ Wl1, const float* __restrict__ Wr1, const float* __restrict__ a1,
    float* __restrict__ ws)
{
    __shared__ float xs[8 * K];
    const int rb   = blockIdx.x;   // 0..63 : 8-row block
    const int inst = blockIdx.y;   // 0..15 (br*8 + batch)
    const int br   = inst >> 3;
    const int tid  = threadIdx.x;
    const int d = tid & 63, ig = tid >> 6;
    const float* Wl = br ? Wl1 : Wl0;
    const float* Wr = br ? Wr1 : Wr0;
    const float* av = br ? a1  : a0;
    const float* sp = src + (size_t)(srcPerInst ? inst : (inst & 7)) * NN * K + (size_t)rb * 8 * K;

    if (tid < 2 * K) ((float4*)xs)[tid] = ((const float4*)sp)[tid];
    __syncthreads();

    float accl[2] = {0.f, 0.f}, accr[2] = {0.f, 0.f};
#pragma unroll 8
    for (int k = 0; k < K; ++k) {
        float wl = Wl[k * 64 + d];            // coalesced, L2-hot
        float wr = Wr[k * 64 + d];
#pragma unroll
        for (int rr = 0; rr < 2; ++rr) {
            float xv = xs[(ig * 2 + rr) * K + k];   // wave-uniform broadcast
            accl[rr] = fmaf(xv, wl, accl[rr]);
            accr[rr] = fmaf(xv, wr, accr[rr]);
        }
    }

    float aval = av[d];
    float* XLI = ws + OFF_XLI; float* XR = ws + OFF_XR;
    float* VV  = ws + OFF_VV;  float* SA = ws + OFF_SA;
    __hip_bfloat16* XLTH = (__hip_bfloat16*)(ws + OFF_XLTH);
    __hip_bfloat16* XLTL = (__hip_bfloat16*)(ws + OFF_XLTL);
#pragma unroll
    for (int rr = 0; rr < 2; ++rr) {
        int row = rb * 8 + ig * 2 + rr;
        XR[(size_t)(inst * NN + row) * 64 + d] = accr[rr];
        // interleaved xl for kattn's coalesced per-lane row loads
        XLI[(((size_t)inst * 8 + (row >> 6)) * 16 + (d >> 2)) * 256 + (row & 63) * 4 + (d & 3)] = accl[rr];
        // transposed bf16 hi/lo for the MFMA B-operand
        __hip_bfloat16 h  = __float2bfloat16(accl[rr]);
        __hip_bfloat16 lo = __float2bfloat16(accl[rr] - __bfloat162float(h));
        size_t ot = (size_t)(inst * 64 + d) * NN + row;
        XLTH[ot] = h; XLTL[ot] = lo;
        float pv = aval * accl[rr];
#pragma unroll
        for (int mm = 32; mm > 0; mm >>= 1) pv += __shfl_xor(pv, mm, 64);
        if (d == 0) VV[inst * NN + row] = 0.6f * L2E * pv;   // log2e folded
    }
    if (rb == 0 && ig == 0 && (inst & 7) == 0) SA[br * 64 + d] = 0.4f * L2E * aval;  // log2e folded
}

// ------- fused attention: scalar-path scoring, wave-private p, MFMA PV + den -------
__global__ __launch_bounds__(512, 4) void kattn(
    const float* __restrict__ ws,
    const float* __restrict__ b0, const float* __restrict__ b1,
    float* __restrict__ Hout)
{
    __shared__ __hip_bfloat16 pbuf[8][2048];   // per-wave p: 1024 hi + 1024 lo (32 KB)
    __shared__ float pout[8][1056];            // partial outs [w][i][66] (33 KB)

    const int ib   = blockIdx.x;        // 0..31 : 16 i-rows
    const int inst = blockIdx.y;        // 0..15
    const int br   = inst >> 3;
    const int tid  = threadIdx.x;
    const int lane = tid & 63;
    const int w    = __builtin_amdgcn_readfirstlane(tid >> 6);   // wave id 0..7
    const float* XR  = ws + OFF_XR + (size_t)inst * NN * 64;
    const float* VV  = ws + OFF_VV + inst * NN;
    const float* SAp = ws + OFF_SA + br * 64;
    const __hip_bfloat16* XLTH = (const __hip_bfloat16*)(ws + OFF_XLTH) + (size_t)inst * 64 * NN;
    const __hip_bfloat16* XLTL = (const __hip_bfloat16*)(ws + OFF_XLTL) + (size_t)inst * 64 * NN;
    const float* bias = br ? b1 : b0;

    // per-lane xl row (j = w*64+lane), coalesced from interleaved layout; loaded once
    const float4* xli4 = (const float4*)(ws + OFF_XLI) + ((size_t)inst * 8 + w) * 1024;
    float xlv[64];
#pragma unroll
    for (int q = 0; q < 16; ++q) {
        float4 v = xli4[q * 64 + lane];
        xlv[4*q+0] = v.x; xlv[4*q+1] = v.y; xlv[4*q+2] = v.z; xlv[4*q+3] = v.w;
    }
    float vj = VV[w * 64 + lane];

    __hip_bfloat16* phw = pbuf[w];          // wave-private: no barriers needed
    __hip_bfloat16* plw = pbuf[w] + 1024;

    // ---------------- scoring + p (2 i-rows per iteration) ----------------
    for (int ii = 0; ii < 16; ii += 2) {
        const float* xr0 = XR + (size_t)(ib * 16 + ii) * 64;       // uniform addr -> s_load
        const float* xr1 = xr0 + 64;
        float a0 = 0.f, a1 = 0.f, a2 = 0.f, a3 = 0.f;
        float b0c = 0.f, b1c = 0.f, b2c = 0.f, b3c = 0.f;
#pragma unroll
        for (int q = 0; q < 16; ++q) {
            float4 s4 = ((const float4*)SAp)[q];                   // uniform -> s_load
            float4 r0 = ((const float4*)xr0)[q];                   // uniform -> s_load
            float4 r1 = ((const float4*)xr1)[q];
            a0  = fmaf(s4.x, fabsf(r0.x + xlv[4*q+0]), a0);
            a1  = fmaf(s4.y, fabsf(r0.y + xlv[4*q+1]), a1);
            a2  = fmaf(s4.z, fabsf(r0.z + xlv[4*q+2]), a2);
            a3  = fmaf(s4.w, fabsf(r0.w + xlv[4*q+3]), a3);
            b0c = fmaf(s4.x, fabsf(r1.x + xlv[4*q+0]), b0c);
            b1c = fmaf(s4.y, fabsf(r1.y + xlv[4*q+1]), b1c);
            b2c = fmaf(s4.z, fabsf(r1.z + xlv[4*q+2]), b2c);
            b3c = fmaf(s4.w, fabsf(r1.w + xlv[4*q+3]), b3c);
        }
        float p0 = exp2f(((a0 + a1) + (a2 + a3)) + vj);
        float p1 = exp2f(((b0c + b1c) + (b2c + b3c)) + vj);
#pragma unroll
        for (int u = 0; u < 2; ++u) {
            float p = u ? p1 : p0;
            int r = ii + u;
            __hip_bfloat16 h  = __float2bfloat16(p);
            __hip_bfloat16 lo = __float2bfloat16(p - __bfloat162float(h));
            int idx = r * 64 + (((lane >> 3) ^ (r & 7)) << 3) + (lane & 7);
            phw[idx] = h; plw[idx] = lo;
        }
    }

    // ---------------- PV + den via MFMA (wave-private A-frags) ----------------
    f32x4 accn[4] = {{0,0,0,0},{0,0,0,0},{0,0,0,0},{0,0,0,0}};
    f32x4 accd = {0, 0, 0, 0};
    const short8 ones = {16256,16256,16256,16256,16256,16256,16256,16256};  // bf16 1.0
#pragma unroll
    for (int ks = 0; ks < 2; ++ks) {
        int aidx = (lane & 15) * 64 + ((((ks << 2) + (lane >> 4)) ^ (lane & 7)) << 3);
        short8 ah = *(const short8*)&phw[aidx];
        short8 al = *(const short8*)&plw[aidx];
        int jb = w * 64 + ks * 32 + (lane >> 4) * 8;
#pragma unroll
        for (int dt = 0; dt < 4; ++dt) {
            float4 bhv = *(const float4*)&XLTH[(size_t)(dt * 16 + (lane & 15)) * NN + jb];
            float4 blv = *(const float4*)&XLTL[(size_t)(dt * 16 + (lane & 15)) * NN + jb];
            short8 bh = __builtin_bit_cast(short8, bhv);
            short8 bl = __builtin_bit_cast(short8, blv);
            accn[dt] = __builtin_amdgcn_mfma_f32_16x16x32_bf16(ah, bh, accn[dt], 0, 0, 0);
            accn[dt] = __builtin_amdgcn_mfma_f32_16x16x32_bf16(al, bh, accn[dt], 0, 0, 0);
            accn[dt] = __builtin_amdgcn_mfma_f32_16x16x32_bf16(ah, bl, accn[dt], 0, 0, 0);
        }
        accd = __builtin_amdgcn_mfma_f32_16x16x32_bf16(ah, ones, accd, 0, 0, 0);
        accd = __builtin_amdgcn_mfma_f32_16x16x32_bf16(al, ones, accd, 0, 0, 0);
    }

    // partial outs -> LDS: pout[w][i][66] (d 0..63, den at 64)
    float* pw = pout[w];
#pragma unroll
    for (int dt = 0; dt < 4; ++dt)
#pragma unroll
        for (int r = 0; r < 4; ++r)
            pw[((lane >> 4) * 4 + r) * 66 + dt * 16 + (lane & 15)] = accn[dt][r];
    if ((lane & 15) == 0) {
#pragma unroll
        for (int r = 0; r < 4; ++r)
            pw[((lane >> 4) * 4 + r) * 66 + 64] = accd[r];
    }
    __syncthreads();   // the only barrier: partials visible

    // ---------------- cross-wave reduction + epilogue ----------------
    {
        int i  = tid >> 5;         // 0..15
        int dd = tid & 31;         // d pair
        float s0 = 0.f, s1 = 0.f, dn = 0.f;
#pragma unroll
        for (int ww = 0; ww < 8; ++ww) {
            const float* pb = &pout[ww][i * 66];
            float2 v = *(const float2*)&pb[dd * 2];
            s0 += v.x; s1 += v.y; dn += pb[64];
        }
        float inv = 1.f / dn;
        float v0 = s0 * inv + bias[dd * 2];
        float v1 = s1 * inv + bias[dd * 2 + 1];
        float t0 = 1.f - 2.f / (__expf(2.f * v0) + 1.f);
        float t1 = 1.f - 2.f / (__expf(2.f * v1) + 1.f);
        float2 o = make_float2(t0, t1);
        *(float2*)&Hout[(size_t)(inst * NN + ib * 16 + i) * 64 + dd * 2] = o;
    }
}

// ---------------- mean-pool over nodes ----------------
__global__ __launch_bounds__(1024) void kpool(const float* __restrict__ H2, float* __restrict__ out)
{
    __shared__ float red[16][64];
    const int inst = blockIdx.x;
    const int tid = threadIdx.x, ig = tid >> 6, lane = tid & 63;
    float s = 0.f;
    for (int i = ig; i < NN; i += 16) s += H2[(size_t)(inst * NN + i) * 64 + lane];
    red[ig][lane] = s;
    __syncthreads();
    if (tid < 64) {
        float v = 0.f;
#pragma unroll
        for (int k = 0; k < 16; ++k) v += red[k][tid];
        out[inst * 64 + tid] = v * (1.f / NN);
    }
}

extern "C" void kernel_launch(void* const* d_in, const int* in_sizes, int n_in,
                              void* d_out, int out_size, void* d_ws, size_t ws_size,
                              hipStream_t stream)
{
    (void)in_sizes; (void)n_in; (void)out_size; (void)ws_size;
    const float* feat  = (const float*)d_in[0];
    const float* p1_Wl = (const float*)d_in[1],  *p1_Wr = (const float*)d_in[2];
    const float* p1_a  = (const float*)d_in[3],  *p1_b  = (const float*)d_in[4];
    const float* p2_Wl = (const float*)d_in[5],  *p2_Wr = (const float*)d_in[6];
    const float* p2_a  = (const float*)d_in[7],  *p2_b  = (const float*)d_in[8];
    const float* v1_Wl = (const float*)d_in[9],  *v1_Wr = (const float*)d_in[10];
    const float* v1_a  = (const float*)d_in[11], *v1_b  = (const float*)d_in[12];
    const float* v2_Wl = (const float*)d_in[13], *v2_Wr = (const float*)d_in[14];
    const float* v2_a  = (const float*)d_in[15], *v2_b  = (const float*)d_in[16];

    float* ws = (float*)d_ws;
    float* H1 = ws + OFF_H1;
    float* H2 = ws + OFF_H2;
    float* out = (float*)d_out;

    // layer 1 (input: features, K=128)
    kpre<128><<<dim3(64, 16), 256, 0, stream>>>(feat, 0, p1_Wl, p1_Wr, p1_a,
                                                v1_Wl, v1_Wr, v1_a, ws);
    kattn<<<dim3(32, 16), 512, 0, stream>>>(ws, p1_b, v1_b, H1);
    // layer 2 (input: H1, K=64)
    kpre<64><<<dim3(64, 16), 256, 0, stream>>>(H1, 1, p2_Wl, p2_Wr, p2_a,
                                               v2_Wl, v2_Wr, v2_a, ws);
    kattn<<<dim3(32, 16), 512, 0, stream>>>(ws, p2_b, v2_b, H2);
    // pool
    kpool<<<16, 1024, 0, stream>>>(H2, out);
}